// Round 1
// baseline (132.621 us; speedup 1.0000x reference)
//
#include <hip/hip_runtime.h>

// Disable FMA contraction so float rounding matches the numpy reference
// op-for-op (threshold compares at 0.5 and argmax ties depend on it).
#pragma clang fp contract(off)

#define BB 32     // batch
#define NN 100    // gt boxes per image
#define PP 8732   // priors

__device__ __constant__ float VAR_CXCY = 0.1f;
__device__ __constant__ float VAR_WH   = 0.2f;

// -------------------------------------------------------------------------
// Kernel 1: per (b, gt j), find argmax_p IoU(gt_j, prior_p) with
// first-index tie-break. One wave per gt. Packs (iou_bits, ~p) into u64 so
// unsigned max == (max iou, then min p).
// -------------------------------------------------------------------------
__global__ __launch_bounds__(256) void k_best_prior(
    const float* __restrict__ gt,       // [B,N,4] xyxy
    const float* __restrict__ priors,   // [P,4] cxcywh
    unsigned long long* __restrict__ best_key)  // [B,N]
{
    const int wave = blockIdx.x * 4 + (threadIdx.x >> 6);
    const int lane = threadIdx.x & 63;
    if (wave >= BB * NN) return;
    const int b = wave / NN;
    const int j = wave % NN;

    const float4 g = reinterpret_cast<const float4*>(gt)[b * NN + j];
    const float gx1 = g.x, gy1 = g.y, gx2 = g.z, gy2 = g.w;
    const float area_a = (gx2 - gx1) * (gy2 - gy1);

    unsigned long long best = 0ull;
    for (int p = lane; p < PP; p += 64) {
        float4 pr = reinterpret_cast<const float4*>(priors)[p];
        // point_form: exact /2 == *0.5f
        float px1 = pr.x - pr.z * 0.5f;
        float py1 = pr.y - pr.w * 0.5f;
        float px2 = pr.x + pr.z * 0.5f;
        float py2 = pr.y + pr.w * 0.5f;
        float ltx = fmaxf(gx1, px1), lty = fmaxf(gy1, py1);
        float rbx = fminf(gx2, px2), rby = fminf(gy2, py2);
        float w = fmaxf(rbx - ltx, 0.0f), h = fmaxf(rby - lty, 0.0f);
        float inter = w * h;
        float area_b = (px2 - px1) * (py2 - py1);
        float iou = inter / (area_a + area_b - inter + 1e-6f);
        unsigned long long key =
            ((unsigned long long)__float_as_uint(iou) << 32) |
            (unsigned int)(~p);
        if (key > best) best = key;
    }

    // 64-lane butterfly max-reduce (split u64 into two u32 shuffles)
    for (int off = 32; off; off >>= 1) {
        unsigned int lo = (unsigned int)best;
        unsigned int hi = (unsigned int)(best >> 32);
        unsigned int olo = __shfl_xor(lo, off);
        unsigned int ohi = __shfl_xor(hi, off);
        unsigned long long other = ((unsigned long long)ohi << 32) | olo;
        if (other > best) best = other;
    }
    if (lane == 0) best_key[b * NN + j] = best;
}

// -------------------------------------------------------------------------
// Kernel 2: per (b, p): column max+argmax over gts (first-occurrence),
// force-match (last-write-wins over j, i.e. max j), encode, write out.
// -------------------------------------------------------------------------
__global__ __launch_bounds__(256) void k_match_encode(
    const float* __restrict__ gt,       // [B,N,4]
    const int*   __restrict__ labels,   // [B,N]
    const float* __restrict__ priors,   // [P,4]
    const unsigned long long* __restrict__ best_key,  // [B,N]
    float* __restrict__ loc_out,        // [B,P,4]
    float* __restrict__ conf_out)       // [B,P]
{
    __shared__ float4 s_gt[NN];
    __shared__ float  s_area[NN];
    __shared__ int    s_lab[NN];
    __shared__ int    s_kp[NN];   // best prior index for gt j

    const int b = blockIdx.y;
    const int t = threadIdx.x;
    if (t < NN) {
        float4 g = reinterpret_cast<const float4*>(gt)[b * NN + t];
        s_gt[t] = g;
        s_area[t] = (g.z - g.x) * (g.w - g.y);
        s_lab[t] = labels[b * NN + t];
        unsigned int v = (unsigned int)(best_key[b * NN + t] & 0xFFFFFFFFull);
        s_kp[t] = (int)(~v);      // recover p
    }
    __syncthreads();

    const int p = blockIdx.x * 256 + t;
    if (p >= PP) return;

    const float4 pr = reinterpret_cast<const float4*>(priors)[p];
    const float px1 = pr.x - pr.z * 0.5f;
    const float py1 = pr.y - pr.w * 0.5f;
    const float px2 = pr.x + pr.z * 0.5f;
    const float py2 = pr.y + pr.w * 0.5f;
    const float area_b = (px2 - px1) * (py2 - py1);

    float best_ov = -1.0f;
    int best_j = 0;
    int forced_j = -1;

    #pragma unroll 4
    for (int j = 0; j < NN; ++j) {
        float4 g = s_gt[j];
        float ltx = fmaxf(g.x, px1), lty = fmaxf(g.y, py1);
        float rbx = fminf(g.z, px2), rby = fminf(g.w, py2);
        float w = fmaxf(rbx - ltx, 0.0f), h = fmaxf(rby - lty, 0.0f);
        float inter = w * h;
        float iou = inter / (s_area[j] + area_b - inter + 1e-6f);
        if (iou > best_ov) { best_ov = iou; best_j = j; }  // strict > = first occurrence
        if (s_kp[j] == p) forced_j = j;                    // ascending j = last-write-wins
    }

    const int j = (forced_j >= 0) ? forced_j : best_j;
    // forced priors have ov := 2.0 (>= 0.5) so they are never background
    const int conf = (forced_j < 0 && best_ov < 0.5f) ? 0 : (s_lab[j] + 1);

    const float4 m = s_gt[j];
    const float mcx = (m.x + m.z) * 0.5f;
    const float mcy = (m.y + m.w) * 0.5f;
    const float mw  = fmaxf(m.z - m.x, 1e-6f);
    const float mh  = fmaxf(m.w - m.y, 1e-6f);
    const float gcx = (mcx - pr.x) / (VAR_CXCY * pr.z);
    const float gcy = (mcy - pr.y) / (VAR_CXCY * pr.w);
    const float gw  = logf(mw / pr.z) / VAR_WH;
    const float gh  = logf(mh / pr.w) / VAR_WH;

    reinterpret_cast<float4*>(loc_out)[b * PP + p] =
        make_float4(gcx, gcy, gw, gh);
    conf_out[b * PP + p] = (float)conf;
}

extern "C" void kernel_launch(void* const* d_in, const int* in_sizes, int n_in,
                              void* d_out, int out_size, void* d_ws, size_t ws_size,
                              hipStream_t stream) {
    const float* gt     = (const float*)d_in[0];  // [32,100,4] f32
    const int*   labels = (const int*)  d_in[1];  // [32,100] i32
    const float* priors = (const float*)d_in[2];  // [8732,4] f32

    float* loc  = (float*)d_out;                  // [32,8732,4]
    float* conf = (float*)d_out + (size_t)BB * PP * 4;  // [32,8732]
    unsigned long long* best_key = (unsigned long long*)d_ws;  // [32,100]

    // K1: one wave per (b, j): 3200 waves = 800 blocks of 4 waves
    dim3 g1((BB * NN + 3) / 4);
    k_best_prior<<<g1, 256, 0, stream>>>(gt, priors, best_key);

    // K2: one thread per (b, p)
    dim3 g2((PP + 255) / 256, BB);
    k_match_encode<<<g2, 256, 0, stream>>>(gt, labels, priors, best_key,
                                           loc, conf);
}

// Round 2
// 117.600 us; speedup vs baseline: 1.1277x; 1.1277x over previous
//
#include <hip/hip_runtime.h>

// Disable FMA contraction so float rounding matches the numpy reference
// op-for-op (threshold compares at 0.5 and argmax ties depend on it).
#pragma clang fp contract(off)

#define BB 32     // batch
#define NN 100    // gt boxes per image
#define PP 8732   // priors

// -------------------------------------------------------------------------
// Kernel 1 (fused IoU pass): thread owns prior p of batch b.
//  - column max/argmax over gts (first-occurrence, strict >) -> m8 byte
//  - row max/argmax over priors via wave shuffle-max + ballot (min-p
//    tie-break since lanes are ordered by p), cross-wave via LDS slots,
//    cross-block via one u64 atomicMax per (block, j).
// Key = (iou_bits << 32) | ~p : u64 max == (max iou, then min p).
// -------------------------------------------------------------------------
__global__ __launch_bounds__(256) void k_iou_pass(
    const float* __restrict__ gt,        // [B,N,4] xyxy
    const float* __restrict__ priors,    // [P,4] cxcywh
    unsigned long long* __restrict__ gkey,  // [B,N], pre-zeroed
    unsigned char* __restrict__ m8)         // [B,P]: best_j | (bg?0x80:0)
{
    __shared__ float4 s_gt[NN];
    __shared__ float  s_area[NN];
    __shared__ unsigned long long s_rk[4][NN];

    const int b    = blockIdx.y;
    const int t    = threadIdx.x;
    const int lane = t & 63;
    const int wid  = t >> 6;
    const int p    = blockIdx.x * 256 + t;
    const bool valid = p < PP;

    if (t < NN) {
        float4 g = reinterpret_cast<const float4*>(gt)[b * NN + t];
        s_gt[t] = g;
        s_area[t] = (g.z - g.x) * (g.w - g.y);
    }
    __syncthreads();

    const int pc = valid ? p : (PP - 1);
    const float4 pr = reinterpret_cast<const float4*>(priors)[pc];
    const float px1 = pr.x - pr.z * 0.5f;
    const float py1 = pr.y - pr.w * 0.5f;
    const float px2 = pr.x + pr.z * 0.5f;
    const float py2 = pr.y + pr.w * 0.5f;
    const float area_b = (px2 - px1) * (py2 - py1);

    float best_ov = -1.0f;
    int best_j = 0;

    #pragma unroll 2
    for (int j = 0; j < NN; ++j) {
        float4 g = s_gt[j];
        float ltx = fmaxf(g.x, px1), lty = fmaxf(g.y, py1);
        float rbx = fminf(g.z, px2), rby = fminf(g.w, py2);
        float w = fmaxf(rbx - ltx, 0.0f), h = fmaxf(rby - lty, 0.0f);
        float inter = w * h;
        float iou = inter / (s_area[j] + area_b - inter + 1e-6f);
        if (!valid) iou = -1.0f;          // never wins row max, iou>=0 for valid

        if (iou > best_ov) { best_ov = iou; best_j = j; }  // first occurrence

        // wave row-max for this j
        float wm = iou;
        for (int off = 32; off; off >>= 1)
            wm = fmaxf(wm, __shfl_xor(wm, off));
        unsigned long long mask = __ballot(iou == wm);
        if (lane == __ffsll((unsigned long long)mask) - 1) {
            s_rk[wid][j] = (wm >= 0.0f)
                ? (((unsigned long long)__float_as_uint(wm) << 32) |
                   (unsigned int)(~p))
                : 0ull;                   // whole wave out of range
        }
    }
    __syncthreads();

    if (t < NN) {
        unsigned long long k0 = s_rk[0][t], k1 = s_rk[1][t];
        unsigned long long k2 = s_rk[2][t], k3 = s_rk[3][t];
        unsigned long long ka = k0 > k1 ? k0 : k1;
        unsigned long long kb = k2 > k3 ? k2 : k3;
        unsigned long long k  = ka > kb ? ka : kb;
        atomicMax(&gkey[b * NN + t], k);
    }
    if (valid) {
        m8[b * PP + p] =
            (unsigned char)(best_j | ((best_ov < 0.5f) ? 0x80 : 0));
    }
}

// -------------------------------------------------------------------------
// Kernel 2: resolve forced matches (ascending j = last-write-wins, matching
// the reference scatter) and encode. No IoU recompute.
// -------------------------------------------------------------------------
__global__ __launch_bounds__(256) void k_encode(
    const float* __restrict__ gt,        // [B,N,4]
    const int*   __restrict__ labels,    // [B,N]
    const float* __restrict__ priors,    // [P,4]
    const unsigned long long* __restrict__ gkey,  // [B,N]
    const unsigned char* __restrict__ m8,         // [B,P]
    float* __restrict__ loc_out,         // [B,P,4]
    float* __restrict__ conf_out)        // [B,P]
{
    __shared__ float4 s_gt[NN];
    __shared__ int    s_lab[NN];
    __shared__ int    s_kp[NN];

    const int b = blockIdx.y;
    const int t = threadIdx.x;
    if (t < NN) {
        s_gt[t] = reinterpret_cast<const float4*>(gt)[b * NN + t];
        s_lab[t] = labels[b * NN + t];
        unsigned int lo = (unsigned int)(gkey[b * NN + t] & 0xFFFFFFFFull);
        s_kp[t] = (int)(~lo);            // winning prior for gt t
    }
    __syncthreads();

    const int p = blockIdx.x * 256 + t;
    if (p >= PP) return;

    int forced_j = -1;
    #pragma unroll 4
    for (int j = 0; j < NN; ++j)
        if (s_kp[j] == p) forced_j = j;

    const unsigned char m = m8[b * PP + p];
    const int j    = (forced_j >= 0) ? forced_j : (m & 0x7f);
    const int conf = (forced_j < 0 && (m & 0x80)) ? 0 : (s_lab[j] + 1);

    const float4 pr = reinterpret_cast<const float4*>(priors)[p];
    const float4 g  = s_gt[j];
    const float mcx = (g.x + g.z) * 0.5f;
    const float mcy = (g.y + g.w) * 0.5f;
    const float mw  = fmaxf(g.z - g.x, 1e-6f);
    const float mh  = fmaxf(g.w - g.y, 1e-6f);
    const float gcx = (mcx - pr.x) / (0.1f * pr.z);
    const float gcy = (mcy - pr.y) / (0.1f * pr.w);
    const float gw  = logf(mw / pr.z) / 0.2f;
    const float gh  = logf(mh / pr.w) / 0.2f;

    reinterpret_cast<float4*>(loc_out)[b * PP + p] =
        make_float4(gcx, gcy, gw, gh);
    conf_out[b * PP + p] = (float)conf;
}

extern "C" void kernel_launch(void* const* d_in, const int* in_sizes, int n_in,
                              void* d_out, int out_size, void* d_ws, size_t ws_size,
                              hipStream_t stream) {
    const float* gt     = (const float*)d_in[0];  // [32,100,4] f32
    const int*   labels = (const int*)  d_in[1];  // [32,100] i32
    const float* priors = (const float*)d_in[2];  // [8732,4] f32

    float* loc  = (float*)d_out;                         // [32,8732,4]
    float* conf = (float*)d_out + (size_t)BB * PP * 4;   // [32,8732]

    unsigned long long* gkey = (unsigned long long*)d_ws;         // [32,100]
    unsigned char* m8 = (unsigned char*)d_ws + (size_t)BB * NN * 8;  // [32,8732]

    // keys must start at 0 for atomicMax (ws is poisoned 0xAA each call)
    hipMemsetAsync(gkey, 0, (size_t)BB * NN * 8, stream);

    dim3 grid((PP + 255) / 256, BB);
    k_iou_pass<<<grid, 256, 0, stream>>>(gt, priors, gkey, m8);
    k_encode<<<grid, 256, 0, stream>>>(gt, labels, priors, gkey, m8, loc, conf);
}

// Round 3
// 105.077 us; speedup vs baseline: 1.2621x; 1.1192x over previous
//
#include <hip/hip_runtime.h>

// Disable FMA contraction so float rounding matches the numpy reference
// op-for-op (threshold compares at 0.5 and argmax ties depend on it).
#pragma clang fp contract(off)

#define BB 32     // batch
#define NN 100    // gt boxes per image
#define PP 8732   // priors
#define CH 16     // j-chunk for the transposed row-max reduce
#define LDW 257   // padded row stride (u32) -> 2-way banks only (free)

// -------------------------------------------------------------------------
// Kernel 1: thread owns prior p of batch b.
//  - GT boxes read via wave-uniform (scalar) loads - no LDS staging.
//  - column max/argmax over gts (first-occurrence, strict >) -> m8 byte
//  - row max over priors: per 16-j chunk, threads write iou bits to LDS
//    (1 ds_write_b32/j, conflict-free), then a 2-phase in-LDS reduce with
//    (iou_bits<<32)|~p u64 keys (max == max-iou then min-p), one
//    atomicMax per (block, j).
// -------------------------------------------------------------------------
__global__ __launch_bounds__(256) void k_iou_pass(
    const float* __restrict__ gt,        // [B,N,4] xyxy
    const float* __restrict__ priors,    // [P,4] cxcywh
    unsigned long long* __restrict__ gkey,  // [B,N], pre-zeroed
    unsigned char* __restrict__ m8)         // [B,P]: best_j | (bg?0x80:0)
{
    __shared__ unsigned int s_iou[CH * LDW];          // 16.4 KB
    __shared__ unsigned long long s_part[CH][17];     // padded, 2.2 KB

    const int b = blockIdx.y;
    const int t = threadIdx.x;
    const int p = blockIdx.x * 256 + t;
    const bool valid = p < PP;
    const int pc = valid ? p : (PP - 1);

    const float4 pr = reinterpret_cast<const float4*>(priors)[pc];
    const float px1 = pr.x - pr.z * 0.5f;
    const float py1 = pr.y - pr.w * 0.5f;
    const float px2 = pr.x + pr.z * 0.5f;
    const float py2 = pr.y + pr.w * 0.5f;
    const float area_b = (px2 - px1) * (py2 - py1);

    // wave-uniform base: compiler scalarizes these loads (s_load_dwordx4)
    const float4* __restrict__ gtb =
        reinterpret_cast<const float4*>(gt) + b * NN;

    float best_ov = -1.0f;
    int best_j = 0;

    for (int jc = 0; jc < NN; jc += CH) {
        const int nr = min(NN - jc, CH);   // rows in this chunk

        #pragma unroll 4
        for (int jj = 0; jj < nr; ++jj) {
            const int j = jc + jj;
            float4 g = gtb[j];                       // uniform -> SGPRs
            float area_a = (g.z - g.x) * (g.w - g.y);
            float ltx = fmaxf(g.x, px1), lty = fmaxf(g.y, py1);
            float rbx = fminf(g.z, px2), rby = fminf(g.w, py2);
            float w = fmaxf(rbx - ltx, 0.0f), h = fmaxf(rby - lty, 0.0f);
            float inter = w * h;
            float iou = inter / (area_a + area_b - inter + 1e-6f);
            if (!valid) iou = 0.0f;       // ties lose to valid via min-p
            if (iou > best_ov) { best_ov = iou; best_j = j; }
            s_iou[jj * LDW + t] = __float_as_uint(iou);  // iou>=0: uint order
        }
        __syncthreads();

        // phase A: 16 threads per row, each scans 16 ascending-p columns
        {
            const int r = t & 15;
            const int s = t >> 4;
            if (r < nr) {
                const unsigned int* row = s_iou + r * LDW + s * 16;
                unsigned int bb = row[0];
                int bi = 0;
                #pragma unroll
                for (int i = 1; i < 16; ++i) {
                    unsigned int v = row[i];
                    if (v > bb) { bb = v; bi = i; }   // strict > = min p
                }
                int pw = blockIdx.x * 256 + s * 16 + bi;
                s_part[r][s] = ((unsigned long long)bb << 32) |
                               (unsigned int)(~pw);
            }
        }
        __syncthreads();

        // phase B: one thread per row merges 16 seg partials, one atomic
        if (t < nr) {
            unsigned long long best = s_part[t][0];
            #pragma unroll
            for (int s = 1; s < 16; ++s) {
                unsigned long long k = s_part[t][s];
                if (k > best) best = k;               // ~p breaks iou ties
            }
            atomicMax(&gkey[b * NN + jc + t], best);
        }
        __syncthreads();   // protect s_iou/s_part for next chunk
    }

    if (valid) {
        m8[b * PP + p] =
            (unsigned char)(best_j | ((best_ov < 0.5f) ? 0x80 : 0));
    }
}

// -------------------------------------------------------------------------
// Kernel 2: resolve forced matches (ascending j = last-write-wins, matching
// the reference scatter) via scalar loads - no LDS - then encode.
// -------------------------------------------------------------------------
__global__ __launch_bounds__(256) void k_encode(
    const float* __restrict__ gt,        // [B,N,4]
    const int*   __restrict__ labels,    // [B,N]
    const float* __restrict__ priors,    // [P,4]
    const unsigned long long* __restrict__ gkey,  // [B,N]
    const unsigned char* __restrict__ m8,         // [B,P]
    float* __restrict__ loc_out,         // [B,P,4]
    float* __restrict__ conf_out)        // [B,P]
{
    const int b = blockIdx.y;
    const int t = threadIdx.x;
    const int p = blockIdx.x * 256 + t;
    if (p >= PP) return;

    const unsigned long long* __restrict__ gk = gkey + b * NN;

    int forced_j = -1;
    #pragma unroll 4
    for (int j = 0; j < NN; ++j) {
        int kp = (int)~(unsigned int)(gk[j]);   // uniform -> s_load
        if (kp == p) forced_j = j;              // ascending j = last wins
    }

    const unsigned char m = m8[b * PP + p];
    const int j    = (forced_j >= 0) ? forced_j : (m & 0x7f);
    const int lab  = labels[b * NN + j];
    const int conf = (forced_j < 0 && (m & 0x80)) ? 0 : (lab + 1);

    const float4 pr = reinterpret_cast<const float4*>(priors)[p];
    const float4 g  = reinterpret_cast<const float4*>(gt)[b * NN + j];
    const float mcx = (g.x + g.z) * 0.5f;
    const float mcy = (g.y + g.w) * 0.5f;
    const float mw  = fmaxf(g.z - g.x, 1e-6f);
    const float mh  = fmaxf(g.w - g.y, 1e-6f);
    const float gcx = (mcx - pr.x) / (0.1f * pr.z);
    const float gcy = (mcy - pr.y) / (0.1f * pr.w);
    const float gw  = logf(mw / pr.z) / 0.2f;
    const float gh  = logf(mh / pr.w) / 0.2f;

    reinterpret_cast<float4*>(loc_out)[b * PP + p] =
        make_float4(gcx, gcy, gw, gh);
    conf_out[b * PP + p] = (float)conf;
}

extern "C" void kernel_launch(void* const* d_in, const int* in_sizes, int n_in,
                              void* d_out, int out_size, void* d_ws, size_t ws_size,
                              hipStream_t stream) {
    const float* gt     = (const float*)d_in[0];  // [32,100,4] f32
    const int*   labels = (const int*)  d_in[1];  // [32,100] i32
    const float* priors = (const float*)d_in[2];  // [8732,4] f32

    float* loc  = (float*)d_out;                         // [32,8732,4]
    float* conf = (float*)d_out + (size_t)BB * PP * 4;   // [32,8732]

    unsigned long long* gkey = (unsigned long long*)d_ws;            // [32,100]
    unsigned char* m8 = (unsigned char*)d_ws + (size_t)BB * NN * 8;  // [32,8732]

    // keys must start at 0 for atomicMax (ws is poisoned 0xAA each call)
    hipMemsetAsync(gkey, 0, (size_t)BB * NN * 8, stream);

    dim3 grid((PP + 255) / 256, BB);
    k_iou_pass<<<grid, 256, 0, stream>>>(gt, priors, gkey, m8);
    k_encode<<<grid, 256, 0, stream>>>(gt, labels, priors, gkey, m8, loc, conf);
}

// Round 4
// 99.742 us; speedup vs baseline: 1.3296x; 1.0535x over previous
//
#include <hip/hip_runtime.h>

// Disable FMA contraction so float rounding matches the numpy reference
// op-for-op (threshold compares at 0.5 and argmax ties depend on it).
#pragma clang fp contract(off)

#define BB 32     // batch
#define NN 100    // gt boxes per image
#define PP 8732   // priors
#define CH 16     // j-chunk for the transposed row-max reduce
#define LDW 257   // padded row stride (u32) -> 2-way banks only (free)

// -------------------------------------------------------------------------
// Kernel 1: thread owns prior p of batch b.
//  - GT boxes read via wave-uniform (scalar) loads - no LDS staging.
//  - column max/argmax over gts (first-occurrence, strict >) -> m8 byte
//  - row max over priors: per 16-j chunk, threads write iou bits to LDS
//    (1 conflict-free ds_write_b32/j), phase A reduces 16 ascending-p
//    columns per thread into persistent s_part[j][seg] u64 keys
//    ((iou_bits<<32)|~p : max == max-iou then min-p). ONE deferred batch
//    of 100 atomicMax at kernel end - atomic latency never sits inside a
//    barrier. 2 barriers per chunk (was 3 + atomic drain).
// -------------------------------------------------------------------------
__global__ __launch_bounds__(256) void k_iou_pass(
    const float* __restrict__ gt,        // [B,N,4] xyxy
    const float* __restrict__ priors,    // [P,4] cxcywh
    unsigned long long* __restrict__ gkey,  // [B,N], pre-zeroed
    unsigned char* __restrict__ m8)         // [B,P]: best_j | (bg?0x80:0)
{
    __shared__ unsigned int s_iou[CH * LDW];          // 16.4 KB
    __shared__ unsigned long long s_part[NN][17];     // 13.6 KB, 2-way banks

    const int b = blockIdx.y;
    const int t = threadIdx.x;
    const int p = blockIdx.x * 256 + t;
    const bool valid = p < PP;
    const int pc = valid ? p : (PP - 1);

    const float4 pr = reinterpret_cast<const float4*>(priors)[pc];
    const float px1 = pr.x - pr.z * 0.5f;
    const float py1 = pr.y - pr.w * 0.5f;
    const float px2 = pr.x + pr.z * 0.5f;
    const float py2 = pr.y + pr.w * 0.5f;
    const float area_b = (px2 - px1) * (py2 - py1);

    // wave-uniform base: compiler scalarizes these loads (s_load_dwordx4)
    const float4* __restrict__ gtb =
        reinterpret_cast<const float4*>(gt) + b * NN;

    float best_ov = -1.0f;
    int best_j = 0;

    for (int jc = 0; jc < NN; jc += CH) {
        const int nr = (NN - jc) < CH ? (NN - jc) : CH;

        #pragma unroll 4
        for (int jj = 0; jj < nr; ++jj) {
            float4 g = gtb[jc + jj];                 // uniform -> SGPRs
            float area_a = (g.z - g.x) * (g.w - g.y);
            float ltx = fmaxf(g.x, px1), lty = fmaxf(g.y, py1);
            float rbx = fminf(g.z, px2), rby = fminf(g.w, py2);
            float w = fmaxf(rbx - ltx, 0.0f), h = fmaxf(rby - lty, 0.0f);
            float inter = w * h;
            float iou = inter / (area_a + area_b - inter + 1e-6f);
            if (!valid) iou = 0.0f;       // ties lose to valid via min-p scan
            if (iou > best_ov) { best_ov = iou; best_j = jc + jj; }
            s_iou[jj * LDW + t] = __float_as_uint(iou);  // iou>=0: uint order
        }
        __syncthreads();

        // phase A: 16 threads per row, each scans 16 ascending-p columns
        {
            const int r = t & 15;
            const int s = t >> 4;
            if (r < nr) {
                const unsigned int* row = s_iou + r * LDW + s * 16;
                unsigned int bb = row[0];
                int bi = 0;
                #pragma unroll
                for (int i = 1; i < 16; ++i) {
                    unsigned int v = row[i];
                    if (v > bb) { bb = v; bi = i; }   // strict > = min p
                }
                int pw = blockIdx.x * 256 + s * 16 + bi;
                s_part[jc + r][s] = ((unsigned long long)bb << 32) |
                                    (unsigned int)(~pw);
            }
        }
        __syncthreads();   // s_iou reusable next chunk
    }

    // deferred phase B: one merge + one atomic per gt, no trailing barrier
    if (t < NN) {
        unsigned long long best = s_part[t][0];
        #pragma unroll
        for (int s = 1; s < 16; ++s) {
            unsigned long long k = s_part[t][s];
            if (k > best) best = k;                   // ~p breaks iou ties
        }
        atomicMax(&gkey[b * NN + t], best);
    }
    if (valid) {
        m8[b * PP + p] =
            (unsigned char)(best_j | ((best_ov < 0.5f) ? 0x80 : 0));
    }
}

// -------------------------------------------------------------------------
// Kernel 2: resolve forced matches via LDS scatter (max j = last-write-wins,
// matching the reference scatter semantics), then encode.
// -------------------------------------------------------------------------
__global__ __launch_bounds__(256) void k_encode(
    const float* __restrict__ gt,        // [B,N,4]
    const int*   __restrict__ labels,    // [B,N]
    const float* __restrict__ priors,    // [P,4]
    const unsigned long long* __restrict__ gkey,  // [B,N]
    const unsigned char* __restrict__ m8,         // [B,P]
    float* __restrict__ loc_out,         // [B,P,4]
    float* __restrict__ conf_out)        // [B,P]
{
    __shared__ int s_forced[256];        // local p -> forced gt j (-1 none)

    const int b = blockIdx.y;
    const int t = threadIdx.x;
    const int p = blockIdx.x * 256 + t;

    s_forced[t] = -1;
    __syncthreads();
    if (t < NN) {
        int kp = (int)~(unsigned int)(gkey[b * NN + t] & 0xFFFFFFFFull);
        int lp = kp - blockIdx.x * 256;
        if ((unsigned)lp < 256u) atomicMax(&s_forced[lp], t);
    }
    __syncthreads();

    if (p >= PP) return;
    const int forced_j = s_forced[t];

    const unsigned char m = m8[b * PP + p];
    const int j    = (forced_j >= 0) ? forced_j : (m & 0x7f);
    const int lab  = labels[b * NN + j];
    const int conf = (forced_j < 0 && (m & 0x80)) ? 0 : (lab + 1);

    const float4 pr = reinterpret_cast<const float4*>(priors)[p];
    const float4 g  = reinterpret_cast<const float4*>(gt)[b * NN + j];
    const float mcx = (g.x + g.z) * 0.5f;
    const float mcy = (g.y + g.w) * 0.5f;
    const float mw  = fmaxf(g.z - g.x, 1e-6f);
    const float mh  = fmaxf(g.w - g.y, 1e-6f);
    const float gcx = (mcx - pr.x) / (0.1f * pr.z);
    const float gcy = (mcy - pr.y) / (0.1f * pr.w);
    const float gw  = logf(mw / pr.z) / 0.2f;
    const float gh  = logf(mh / pr.w) / 0.2f;

    reinterpret_cast<float4*>(loc_out)[b * PP + p] =
        make_float4(gcx, gcy, gw, gh);
    conf_out[b * PP + p] = (float)conf;
}

extern "C" void kernel_launch(void* const* d_in, const int* in_sizes, int n_in,
                              void* d_out, int out_size, void* d_ws, size_t ws_size,
                              hipStream_t stream) {
    const float* gt     = (const float*)d_in[0];  // [32,100,4] f32
    const int*   labels = (const int*)  d_in[1];  // [32,100] i32
    const float* priors = (const float*)d_in[2];  // [8732,4] f32

    float* loc  = (float*)d_out;                         // [32,8732,4]
    float* conf = (float*)d_out + (size_t)BB * PP * 4;   // [32,8732]

    unsigned long long* gkey = (unsigned long long*)d_ws;            // [32,100]
    unsigned char* m8 = (unsigned char*)d_ws + (size_t)BB * NN * 8;  // [32,8732]

    // keys must start at 0 for atomicMax (ws is poisoned 0xAA each call)
    hipMemsetAsync(gkey, 0, (size_t)BB * NN * 8, stream);

    dim3 grid((PP + 255) / 256, BB);
    k_iou_pass<<<grid, 256, 0, stream>>>(gt, priors, gkey, m8);
    k_encode<<<grid, 256, 0, stream>>>(gt, labels, priors, gkey, m8, loc, conf);
}